// Round 3
// baseline (703.933 us; speedup 1.0000x reference)
//
#include <hip/hip_runtime.h>
#include <hip/hip_bf16.h>
#include <stdint.h>

#define MEM_DIM 128
#define MSG_DIM 256
#define NGATE   384   // 3 * MEM_DIM

typedef __attribute__((ext_vector_type(8))) __bf16 bf16x8;
typedef __attribute__((ext_vector_type(4))) float  f32x4;

union B8u { uint32_t u[4]; bf16x8 v; };

__device__ __forceinline__ uint32_t cvt_pk(float lo, float hi) {
    uint32_t r;
    asm("v_cvt_pk_bf16_f32 %0, %1, %2" : "=v"(r) : "v"(lo), "v"(hi));
    return r;
}

// load 8 consecutive f32 and convert to a bf16x8 fragment (RNE)
__device__ __forceinline__ bf16x8 load_cvt8(const float* __restrict__ p) {
    f32x4 a = *(const f32x4*)p;
    f32x4 b = *(const f32x4*)(p + 4);
    B8u r;
    r.u[0] = cvt_pk(a.x, a.y);
    r.u[1] = cvt_pk(a.z, a.w);
    r.u[2] = cvt_pk(b.x, b.y);
    r.u[3] = cvt_pk(b.z, b.w);
    return r.v;
}

__device__ __forceinline__ bf16x8 zero8() {
    B8u r; r.u[0] = r.u[1] = r.u[2] = r.u[3] = 0; return r.v;
}

__device__ __forceinline__ float sigm(float x) {
    return __builtin_amdgcn_rcpf(1.0f + __expf(-x));
}
__device__ __forceinline__ float tanh_fast(float x) {
    return 1.0f - 2.0f * __builtin_amdgcn_rcpf(1.0f + __expf(2.0f * x));
}

// ---------------------------------------------------------------- copy kernel
__global__ void copy_kernel(const f32x4* __restrict__ mem,
                            const f32x4* __restrict__ lu,
                            f32x4* __restrict__ out,
                            int n_mem4, int n_tot4) {
    int stride = gridDim.x * blockDim.x;
    for (int i = blockIdx.x * blockDim.x + threadIdx.x; i < n_tot4; i += stride) {
        f32x4 v = (i < n_mem4) ? __builtin_nontemporal_load(&mem[i])
                               : __builtin_nontemporal_load(&lu[i - n_mem4]);
        __builtin_nontemporal_store(v, &out[i]);
    }
}

// ------------------------------------------------------- weight bf16 convert
__global__ void wconv_kernel(const float* __restrict__ wih,
                             const float* __restrict__ whh,
                             __hip_bfloat16* __restrict__ out) {
    int i = blockIdx.x * 256 + threadIdx.x;
    const int NIH = NGATE * MSG_DIM;       // 98304
    const int NHH = NGATE * MEM_DIM;       // 49152
    if (i < NIH)            out[i] = __float2bfloat16(wih[i]);
    else if (i < NIH + NHH) out[i] = __float2bfloat16(whh[i - NIH]);
}

// ------------------------------------------------------------------ GRU kernel
// block = 256 threads = 4 waves; each wave owns ONE 16-row subtile (BM=64).
// A fragments (x,h) fit in registers (48 VGPRs) with no spilling; blend values
// (hv) for chunk ch+1 are prefetched during chunk ch's MFMA work.
template<bool PRE>
__global__ __launch_bounds__(256, 3)
void gru_kernel(const float* __restrict__ memory,
                const int*   __restrict__ ids,
                const float* __restrict__ msgs,
                const float* __restrict__ ts,
                const float* __restrict__ Wih,    // [384][256] f32
                const float* __restrict__ Whh,    // [384][128] f32
                const float* __restrict__ bih,
                const float* __restrict__ bhh,
                const __hip_bfloat16* __restrict__ WihB,  // [384][256] bf16
                const __hip_bfloat16* __restrict__ WhhB,  // [384][128] bf16
                float* __restrict__ out_mem,
                float* __restrict__ out_lu,
                int U) {
    const int tid  = threadIdx.x;
    const int wave = tid >> 6;
    const int lane = tid & 63;
    const int g    = lane >> 4;   // 0..3
    const int q    = lane & 15;   // 0..15
    const int rb   = blockIdx.x * 64 + wave * 16;

    // timestamp scatter (64 rows per block)
    {
        int u = blockIdx.x * 64 + tid;
        if (tid < 64 && u < U) out_lu[ids[u]] = ts[u];
    }

    // ---- A fragments: x row (K=256 -> 8 k-steps), h row (K=128 -> 4 k-steps)
    bf16x8 xf[8];
    bf16x8 hf[4];
    {
        int r = rb + q;                    // A-operand row = lane&15
        bool ok = (r < U);
        int id = ok ? ids[r] : 0;
        const float* xp = msgs   + (size_t)r  * MSG_DIM;
        const float* hp = memory + (size_t)id * MEM_DIM;
        #pragma unroll
        for (int s = 0; s < 8; ++s)
            xf[s] = ok ? load_cvt8(xp + 32 * s + 8 * g) : zero8();
        #pragma unroll
        for (int s = 0; s < 4; ++s)
            hf[s] = ok ? load_cvt8(hp + 32 * s + 8 * g) : zero8();
    }

    // ids for the C/D rows this lane writes: row = 4*g + j
    int  oid[4];
    bool okw[4];
    #pragma unroll
    for (int j = 0; j < 4; ++j) {
        int r = rb + 4 * g + j;
        okw[j] = (r < U);
        oid[j] = okw[j] ? ids[r] : 0;
    }

    // prefetch blend values for chunk 0 (col = q)
    float hv[4];
    #pragma unroll
    for (int j = 0; j < 4; ++j)
        hv[j] = memory[(size_t)oid[j] * MEM_DIM + q];

    const f32x4 z4 = {0.f, 0.f, 0.f, 0.f};

    // ---- loop over output-column chunks of 16 (8 chunks cover MEM_DIM=128)
    #pragma unroll 1
    for (int ch = 0; ch < 8; ++ch) {
        const int c = ch * 16 + q;          // output col, also B-operand col

        // prefetch next chunk's blend values (covers HBM latency under MFMA)
        float hvn[4];
        if (ch < 7) {
            #pragma unroll
            for (int j = 0; j < 4; ++j)
                hvn[j] = memory[(size_t)oid[j] * MEM_DIM + c + 16];
        }

        f32x4 acc[6];
        #pragma unroll
        for (int k = 0; k < 6; ++k) acc[k] = z4;

        // gi = x @ W_ih^T   (3 gate rows per chunk)
        #pragma unroll
        for (int s = 0; s < 8; ++s) {
            #pragma unroll
            for (int gate = 0; gate < 3; ++gate) {
                size_t off = (size_t)(gate * MEM_DIM + c) * MSG_DIM + 32 * s + 8 * g;
                bf16x8 b = PRE ? *(const bf16x8*)(WihB + off)
                               : load_cvt8(Wih + off);
                acc[gate] = __builtin_amdgcn_mfma_f32_16x16x32_bf16(xf[s], b, acc[gate], 0, 0, 0);
            }
        }
        // gh = h @ W_hh^T
        #pragma unroll
        for (int s = 0; s < 4; ++s) {
            #pragma unroll
            for (int gate = 0; gate < 3; ++gate) {
                size_t off = (size_t)(gate * MEM_DIM + c) * MEM_DIM + 32 * s + 8 * g;
                bf16x8 b = PRE ? *(const bf16x8*)(WhhB + off)
                               : load_cvt8(Whh + off);
                acc[3 + gate] = __builtin_amdgcn_mfma_f32_16x16x32_bf16(hf[s], b, acc[3 + gate], 0, 0, 0);
            }
        }

        // biases (same for all rows, vary by col)
        float bir = bih[c],             bhr = bhh[c];
        float biz = bih[MEM_DIM + c],   bhz = bhh[MEM_DIM + c];
        float bin = bih[2*MEM_DIM + c], bhn = bhh[2*MEM_DIM + c];

        // gate math + scatter store
        #pragma unroll
        for (int j = 0; j < 4; ++j) {
            if (okw[j]) {
                float gr = acc[0][j] + bir + acc[3][j] + bhr;
                float gz = acc[1][j] + biz + acc[4][j] + bhz;
                float rg = sigm(gr);
                float zg = sigm(gz);
                float hn = acc[5][j] + bhn;
                float ng = tanh_fast(acc[2][j] + bin + rg * hn);
                size_t off = (size_t)oid[j] * MEM_DIM + c;
                out_mem[off] = (1.0f - zg) * ng + zg * hv[j];
            }
        }

        #pragma unroll
        for (int j = 0; j < 4; ++j) hv[j] = hvn[j];
    }
}

// ------------------------------------------------------------------- launcher
extern "C" void kernel_launch(void* const* d_in, const int* in_sizes, int n_in,
                              void* d_out, int out_size, void* d_ws, size_t ws_size,
                              hipStream_t stream) {
    const float* memory      = (const float*)d_in[0];
    const float* last_update = (const float*)d_in[1];
    const int*   ids         = (const int*)  d_in[2];
    const float* msgs        = (const float*)d_in[3];
    const float* ts          = (const float*)d_in[4];
    const float* Wih         = (const float*)d_in[5];
    const float* Whh         = (const float*)d_in[6];
    const float* bih         = (const float*)d_in[7];
    const float* bhh         = (const float*)d_in[8];

    const int NN = in_sizes[1];          // 1,000,000 nodes
    const int U  = in_sizes[2];          // 200,000 updates

    float* out_mem = (float*)d_out;
    float* out_lu  = out_mem + (size_t)NN * MEM_DIM;

    // 1) full pass-through copy of memory + last_update into d_out
    int n_mem4 = NN * MEM_DIM / 4;
    int n_tot4 = n_mem4 + NN / 4;
    copy_kernel<<<8192, 256, 0, stream>>>((const f32x4*)memory,
                                          (const f32x4*)last_update,
                                          (f32x4*)d_out, n_mem4, n_tot4);

    // 2) GRU update on the gathered rows, scatter into d_out
    const size_t WBYTES = (size_t)(NGATE * MSG_DIM + NGATE * MEM_DIM) * sizeof(__hip_bfloat16);
    int nb = (U + 63) / 64;
    if (ws_size >= WBYTES) {
        __hip_bfloat16* wb = (__hip_bfloat16*)d_ws;
        wconv_kernel<<<(NGATE * MSG_DIM + NGATE * MEM_DIM) / 256, 256, 0, stream>>>(Wih, Whh, wb);
        gru_kernel<true><<<nb, 256, 0, stream>>>(memory, ids, msgs, ts,
                                                 Wih, Whh, bih, bhh,
                                                 wb, wb + NGATE * MSG_DIM,
                                                 out_mem, out_lu, U);
    } else {
        gru_kernel<false><<<nb, 256, 0, stream>>>(memory, ids, msgs, ts,
                                                  Wih, Whh, bih, bhh,
                                                  nullptr, nullptr,
                                                  out_mem, out_lu, U);
    }
}

// Round 4
// 513.794 us; speedup vs baseline: 1.3701x; 1.3701x over previous
//
#include <hip/hip_runtime.h>
#include <hip/hip_bf16.h>
#include <stdint.h>

#define MEM_DIM 128
#define MSG_DIM 256
#define NGATE   384   // 3 * MEM_DIM

typedef __attribute__((ext_vector_type(8))) __bf16 bf16x8;
typedef __attribute__((ext_vector_type(4))) float  f32x4;

union B8u { uint32_t u[4]; bf16x8 v; };

__device__ __forceinline__ uint32_t cvt_pk(float lo, float hi) {
    uint32_t r;
    asm("v_cvt_pk_bf16_f32 %0, %1, %2" : "=v"(r) : "v"(lo), "v"(hi));
    return r;
}

// load 8 consecutive f32 and convert to a bf16x8 fragment (RNE)
__device__ __forceinline__ bf16x8 load_cvt8(const float* __restrict__ p) {
    f32x4 a = *(const f32x4*)p;
    f32x4 b = *(const f32x4*)(p + 4);
    B8u r;
    r.u[0] = cvt_pk(a.x, a.y);
    r.u[1] = cvt_pk(a.z, a.w);
    r.u[2] = cvt_pk(b.x, b.y);
    r.u[3] = cvt_pk(b.z, b.w);
    return r.v;
}

__device__ __forceinline__ float sigm(float x) {
    return __builtin_amdgcn_rcpf(1.0f + __expf(-x));
}
__device__ __forceinline__ float tanh_fast(float x) {
    return 1.0f - 2.0f * __builtin_amdgcn_rcpf(1.0f + __expf(2.0f * x));
}

// ---------------------------------------------------------------- copy kernel
__global__ void copy_kernel(const f32x4* __restrict__ mem,
                            const f32x4* __restrict__ lu,
                            f32x4* __restrict__ out,
                            int n_mem4, int n_tot4) {
    int stride = gridDim.x * blockDim.x;
    for (int i = blockIdx.x * blockDim.x + threadIdx.x; i < n_tot4; i += stride) {
        // cached load for mem (warms L3 for the gather in gru kernel);
        // nontemporal store (out is never re-read)
        f32x4 v = (i < n_mem4) ? mem[i]
                               : __builtin_nontemporal_load(&lu[i - n_mem4]);
        __builtin_nontemporal_store(v, &out[i]);
    }
}

// ------------------------------------------------------- weight bf16 convert
__global__ void wconv_kernel(const float* __restrict__ wih,
                             const float* __restrict__ whh,
                             __hip_bfloat16* __restrict__ out) {
    int i = blockIdx.x * 256 + threadIdx.x;
    const int NIH = NGATE * MSG_DIM;       // 98304
    const int NHH = NGATE * MEM_DIM;       // 49152
    if (i < NIH)            out[i] = __float2bfloat16(wih[i]);
    else if (i < NIH + NHH) out[i] = __float2bfloat16(whh[i - NIH]);
}

// ------------------------------------------------------- weight-stationary GRU
// 512 threads = 8 waves; wave w owns output-column chunk w (cols w*16..w*16+15).
// Each wave holds its chunk's FULL B operand (W_ih + W_hh, all 3 gates) in
// 144 VGPRs, loaded once and pinned. Persistent blocks grid-stride over
// 16-row tiles; per tile: load A fragments, 36 MFMAs, gate math, scatter.
template<bool PRE>
__global__ __launch_bounds__(512, 2)
void gru_ws_kernel(const float* __restrict__ memory,
                   const int*   __restrict__ ids,
                   const float* __restrict__ msgs,
                   const float* __restrict__ ts,
                   const float* __restrict__ Wih,    // [384][256] f32
                   const float* __restrict__ Whh,    // [384][128] f32
                   const float* __restrict__ bih,
                   const float* __restrict__ bhh,
                   const __hip_bfloat16* __restrict__ WihB,
                   const __hip_bfloat16* __restrict__ WhhB,
                   float* __restrict__ out_mem,
                   float* __restrict__ out_lu,
                   int U, int ntiles) {
    const int tid  = threadIdx.x;
    const int w    = tid >> 6;     // wave index == column chunk
    const int lane = tid & 63;
    const int g    = lane >> 4;    // 0..3
    const int q    = lane & 15;    // 0..15
    const int c    = w * 16 + q;   // this wave's output column (0..127)

    // ---- persistent B fragments (loaded once)
    bf16x8 Bi[8][3];   // W_ih: 8 k-steps x 3 gates
    bf16x8 Bh[4][3];   // W_hh: 4 k-steps x 3 gates
    #pragma unroll
    for (int s = 0; s < 8; ++s)
        #pragma unroll
        for (int gt = 0; gt < 3; ++gt) {
            size_t off = (size_t)(gt * MEM_DIM + c) * MSG_DIM + 32 * s + 8 * g;
            Bi[s][gt] = PRE ? *(const bf16x8*)(WihB + off) : load_cvt8(Wih + off);
        }
    #pragma unroll
    for (int s = 0; s < 4; ++s)
        #pragma unroll
        for (int gt = 0; gt < 3; ++gt) {
            size_t off = (size_t)(gt * MEM_DIM + c) * MEM_DIM + 32 * s + 8 * g;
            Bh[s][gt] = PRE ? *(const bf16x8*)(WhhB + off) : load_cvt8(Whh + off);
        }
    // pin: make fragments opaque so the compiler cannot rematerialize the loads
    #pragma unroll
    for (int s = 0; s < 8; ++s)
        #pragma unroll
        for (int gt = 0; gt < 3; ++gt)
            asm volatile("" : "+v"(Bi[s][gt]));
    #pragma unroll
    for (int s = 0; s < 4; ++s)
        #pragma unroll
        for (int gt = 0; gt < 3; ++gt)
            asm volatile("" : "+v"(Bh[s][gt]));

    // biases for this wave's columns (loop-invariant)
    const float br  = bih[c] + bhh[c];
    const float bz  = bih[MEM_DIM + c] + bhh[MEM_DIM + c];
    const float bin = bih[2 * MEM_DIM + c];
    const float bhn = bhh[2 * MEM_DIM + c];

    const f32x4 z4 = {0.f, 0.f, 0.f, 0.f};

    // ---- grid-stride over 16-row tiles
    for (int t = blockIdx.x; t < ntiles; t += gridDim.x) {
        const int rb = t << 4;

        // timestamp scatter: wave 0, lanes 0..15
        if (w == 0 && lane < 16) {
            int r = rb + lane;
            if (r < U) out_lu[ids[r]] = ts[r];
        }

        // A-operand row for this lane (clamped; out-of-range rows compute
        // garbage that is never stored)
        int rA = rb + q; if (rA >= U) rA = U - 1;
        const int idA = ids[rA];
        const float* xp = msgs   + (size_t)rA  * MSG_DIM;
        const float* hp = memory + (size_t)idA * MEM_DIM;

        bf16x8 xf[8];
        #pragma unroll
        for (int s = 0; s < 8; ++s) xf[s] = load_cvt8(xp + 32 * s + 8 * g);
        bf16x8 hf[4];
        #pragma unroll
        for (int s = 0; s < 4; ++s) hf[s] = load_cvt8(hp + 32 * s + 8 * g);

        // C/D rows this lane writes: row = 4*g + j
        int  oid[4];
        bool okw[4];
        #pragma unroll
        for (int j = 0; j < 4; ++j) {
            int r = rb + 4 * g + j;
            okw[j] = (r < U);
            oid[j] = ids[(r < U) ? r : (U - 1)];
        }
        // blend values (old h at this lane's output coords); L1-hot from the
        // hf gather above
        float hv[4];
        #pragma unroll
        for (int j = 0; j < 4; ++j)
            hv[j] = memory[(size_t)oid[j] * MEM_DIM + c];

        f32x4 acc[6];
        #pragma unroll
        for (int k = 0; k < 6; ++k) acc[k] = z4;

        #pragma unroll
        for (int s = 0; s < 8; ++s)
            #pragma unroll
            for (int gt = 0; gt < 3; ++gt)
                acc[gt] = __builtin_amdgcn_mfma_f32_16x16x32_bf16(xf[s], Bi[s][gt], acc[gt], 0, 0, 0);
        #pragma unroll
        for (int s = 0; s < 4; ++s)
            #pragma unroll
            for (int gt = 0; gt < 3; ++gt)
                acc[3 + gt] = __builtin_amdgcn_mfma_f32_16x16x32_bf16(hf[s], Bh[s][gt], acc[3 + gt], 0, 0, 0);

        // gate math + scatter store
        #pragma unroll
        for (int j = 0; j < 4; ++j) {
            if (okw[j]) {
                float gr = acc[0][j] + acc[3][j] + br;
                float gz = acc[1][j] + acc[4][j] + bz;
                float rg = sigm(gr);
                float zg = sigm(gz);
                float hn = acc[5][j] + bhn;
                float ng = tanh_fast(acc[2][j] + bin + rg * hn);
                out_mem[(size_t)oid[j] * MEM_DIM + c] = (1.0f - zg) * ng + zg * hv[j];
            }
        }
    }
}

// ------------------------------------------------------------------- launcher
extern "C" void kernel_launch(void* const* d_in, const int* in_sizes, int n_in,
                              void* d_out, int out_size, void* d_ws, size_t ws_size,
                              hipStream_t stream) {
    const float* memory      = (const float*)d_in[0];
    const float* last_update = (const float*)d_in[1];
    const int*   ids         = (const int*)  d_in[2];
    const float* msgs        = (const float*)d_in[3];
    const float* ts          = (const float*)d_in[4];
    const float* Wih         = (const float*)d_in[5];
    const float* Whh         = (const float*)d_in[6];
    const float* bih         = (const float*)d_in[7];
    const float* bhh         = (const float*)d_in[8];

    const int NN = in_sizes[1];          // 1,000,000 nodes
    const int U  = in_sizes[2];          // 200,000 updates

    float* out_mem = (float*)d_out;
    float* out_lu  = out_mem + (size_t)NN * MEM_DIM;

    // 1) full pass-through copy of memory + last_update into d_out
    int n_mem4 = NN * MEM_DIM / 4;
    int n_tot4 = n_mem4 + NN / 4;
    copy_kernel<<<8192, 256, 0, stream>>>((const f32x4*)memory,
                                          (const f32x4*)last_update,
                                          (f32x4*)d_out, n_mem4, n_tot4);

    // 2) weight-stationary GRU update, scatter into d_out
    const size_t WBYTES = (size_t)(NGATE * MSG_DIM + NGATE * MEM_DIM) * sizeof(__hip_bfloat16);
    int ntiles = (U + 15) / 16;
    if (ws_size >= WBYTES) {
        __hip_bfloat16* wb = (__hip_bfloat16*)d_ws;
        wconv_kernel<<<(NGATE * MSG_DIM + NGATE * MEM_DIM) / 256, 256, 0, stream>>>(Wih, Whh, wb);
        gru_ws_kernel<true><<<256, 512, 0, stream>>>(memory, ids, msgs, ts,
                                                     Wih, Whh, bih, bhh,
                                                     wb, wb + NGATE * MSG_DIM,
                                                     out_mem, out_lu, U, ntiles);
    } else {
        gru_ws_kernel<false><<<256, 512, 0, stream>>>(memory, ids, msgs, ts,
                                                      Wih, Whh, bih, bhh,
                                                      nullptr, nullptr,
                                                      out_mem, out_lu, U, ntiles);
    }
}

// Round 5
// 498.572 us; speedup vs baseline: 1.4119x; 1.0305x over previous
//
#include <hip/hip_runtime.h>
#include <hip/hip_bf16.h>
#include <stdint.h>

#define MEM_DIM 128
#define MSG_DIM 256
#define NGATE   384   // 3 * MEM_DIM

typedef __attribute__((ext_vector_type(8))) __bf16 bf16x8;
typedef __attribute__((ext_vector_type(4))) float  f32x4;

union B8u { uint32_t u[4]; bf16x8 v; };

__device__ __forceinline__ uint32_t cvt_pk(float lo, float hi) {
    uint32_t r;
    asm("v_cvt_pk_bf16_f32 %0, %1, %2" : "=v"(r) : "v"(lo), "v"(hi));
    return r;
}

// load 8 consecutive f32 and convert to a bf16x8 fragment (RNE)
__device__ __forceinline__ bf16x8 load_cvt8(const float* __restrict__ p) {
    f32x4 a = *(const f32x4*)p;
    f32x4 b = *(const f32x4*)(p + 4);
    B8u r;
    r.u[0] = cvt_pk(a.x, a.y);
    r.u[1] = cvt_pk(a.z, a.w);
    r.u[2] = cvt_pk(b.x, b.y);
    r.u[3] = cvt_pk(b.z, b.w);
    return r.v;
}

__device__ __forceinline__ float sigm(float x) {
    return __builtin_amdgcn_rcpf(1.0f + __expf(-x));
}
__device__ __forceinline__ float tanh_fast(float x) {
    return 1.0f - 2.0f * __builtin_amdgcn_rcpf(1.0f + __expf(2.0f * x));
}

// ------------------------------------------------------------- bitmap kernels
__global__ void bm_zero_kernel(uint32_t* __restrict__ bm, int nwords) {
    int i = blockIdx.x * 256 + threadIdx.x;
    if (i < nwords) bm[i] = 0;
}
__global__ void bm_set_kernel(const int* __restrict__ ids, uint32_t* __restrict__ bm, int U) {
    int i = blockIdx.x * 256 + threadIdx.x;
    if (i < U) {
        int id = ids[i];
        atomicOr(&bm[id >> 5], 1u << (id & 31));
    }
}

// ----------------------------------------------- copy kernel (skips updated)
// mem rows: 32 x 16B chunks per row; lu: one node per thread.
__global__ void copy_skip_kernel(const f32x4* __restrict__ mem,
                                 const float* __restrict__ lu,
                                 f32x4* __restrict__ outm,
                                 float* __restrict__ outlu,
                                 const uint32_t* __restrict__ bm,
                                 int NN) {
    const int64_t n_mem_chunks = (int64_t)NN * 32;   // 512 B rows / 16 B
    const int64_t total = n_mem_chunks + NN;
    const int64_t stride = (int64_t)gridDim.x * blockDim.x;
    for (int64_t i = (int64_t)blockIdx.x * blockDim.x + threadIdx.x; i < total; i += stride) {
        if (i < n_mem_chunks) {
            int row = (int)(i >> 5);
            if (!((bm[row >> 5] >> (row & 31)) & 1u)) {
                f32x4 v = __builtin_nontemporal_load(&mem[i]);
                __builtin_nontemporal_store(v, &outm[i]);
            }
        } else {
            int node = (int)(i - n_mem_chunks);
            if (!((bm[node >> 5] >> (node & 31)) & 1u))
                outlu[node] = lu[node];
        }
    }
}

// fallback full copy (no workspace for bitmap)
__global__ void copy_all_kernel(const f32x4* __restrict__ mem,
                                const f32x4* __restrict__ lu,
                                f32x4* __restrict__ out,
                                int n_mem4, int n_tot4) {
    int stride = gridDim.x * blockDim.x;
    for (int i = blockIdx.x * blockDim.x + threadIdx.x; i < n_tot4; i += stride) {
        f32x4 v = (i < n_mem4) ? mem[i]
                               : __builtin_nontemporal_load(&lu[i - n_mem4]);
        __builtin_nontemporal_store(v, &out[i]);
    }
}

// ------------------------------------------------------- weight bf16 convert
__global__ void wconv_kernel(const float* __restrict__ wih,
                             const float* __restrict__ whh,
                             __hip_bfloat16* __restrict__ out) {
    int i = blockIdx.x * 256 + threadIdx.x;
    const int NIH = NGATE * MSG_DIM;       // 98304
    const int NHH = NGATE * MEM_DIM;       // 49152
    if (i < NIH)            out[i] = __float2bfloat16(wih[i]);
    else if (i < NIH + NHH) out[i] = __float2bfloat16(whh[i - NIH]);
}

// ------------------------------------------------------- weight-stationary GRU
// 512 threads = 8 waves; wave w owns output-column chunk w. Each wave holds its
// chunk's FULL B operand (144 VGPRs) resident. amdgpu_waves_per_eu(2,2) pins
// the backend's occupancy target to 2 waves/EU -> 256-VGPR budget, no spills.
template<bool PRE>
__global__ __launch_bounds__(512)
__attribute__((amdgpu_waves_per_eu(2, 2)))
void gru_ws_kernel(const float* __restrict__ memory,
                   const int*   __restrict__ ids,
                   const float* __restrict__ msgs,
                   const float* __restrict__ ts,
                   const float* __restrict__ Wih,    // [384][256] f32
                   const float* __restrict__ Whh,    // [384][128] f32
                   const float* __restrict__ bih,
                   const float* __restrict__ bhh,
                   const __hip_bfloat16* __restrict__ WihB,
                   const __hip_bfloat16* __restrict__ WhhB,
                   float* __restrict__ out_mem,
                   float* __restrict__ out_lu,
                   int U, int ntiles) {
    const int tid  = threadIdx.x;
    const int w    = tid >> 6;     // wave index == column chunk
    const int lane = tid & 63;
    const int g    = lane >> 4;    // 0..3
    const int q    = lane & 15;    // 0..15
    const int c    = w * 16 + q;   // this wave's output column (0..127)

    // ---- persistent B fragments (loaded once)
    bf16x8 Bi[8][3];   // W_ih: 8 k-steps x 3 gates
    bf16x8 Bh[4][3];   // W_hh: 4 k-steps x 3 gates
    #pragma unroll
    for (int s = 0; s < 8; ++s)
        #pragma unroll
        for (int gt = 0; gt < 3; ++gt) {
            size_t off = (size_t)(gt * MEM_DIM + c) * MSG_DIM + 32 * s + 8 * g;
            Bi[s][gt] = PRE ? *(const bf16x8*)(WihB + off) : load_cvt8(Wih + off);
        }
    #pragma unroll
    for (int s = 0; s < 4; ++s)
        #pragma unroll
        for (int gt = 0; gt < 3; ++gt) {
            size_t off = (size_t)(gt * MEM_DIM + c) * MEM_DIM + 32 * s + 8 * g;
            Bh[s][gt] = PRE ? *(const bf16x8*)(WhhB + off) : load_cvt8(Whh + off);
        }
    // pin: make fragments opaque so the compiler cannot rematerialize the loads
    #pragma unroll
    for (int s = 0; s < 8; ++s)
        #pragma unroll
        for (int gt = 0; gt < 3; ++gt)
            asm volatile("" : "+v"(Bi[s][gt]));
    #pragma unroll
    for (int s = 0; s < 4; ++s)
        #pragma unroll
        for (int gt = 0; gt < 3; ++gt)
            asm volatile("" : "+v"(Bh[s][gt]));

    // biases for this wave's columns (loop-invariant)
    const float br  = bih[c] + bhh[c];
    const float bz  = bih[MEM_DIM + c] + bhh[MEM_DIM + c];
    const float bin = bih[2 * MEM_DIM + c];
    const float bhn = bhh[2 * MEM_DIM + c];

    const f32x4 z4 = {0.f, 0.f, 0.f, 0.f};

    // ---- grid-stride over 16-row tiles
    for (int t = blockIdx.x; t < ntiles; t += gridDim.x) {
        const int rb = t << 4;

        // timestamp scatter: wave 0, lanes 0..15
        if (w == 0 && lane < 16) {
            int r = rb + lane;
            if (r < U) out_lu[ids[r]] = ts[r];
        }

        // A-operand row for this lane (clamped; out-of-range rows compute
        // garbage that is never stored)
        int rA = rb + q; if (rA >= U) rA = U - 1;
        const int idA = ids[rA];
        const float* xp = msgs   + (size_t)rA  * MSG_DIM;
        const float* hp = memory + (size_t)idA * MEM_DIM;

        bf16x8 xf[8];
        #pragma unroll
        for (int s = 0; s < 8; ++s) xf[s] = load_cvt8(xp + 32 * s + 8 * g);
        bf16x8 hf[4];
        #pragma unroll
        for (int s = 0; s < 4; ++s) hf[s] = load_cvt8(hp + 32 * s + 8 * g);

        // C/D rows this lane writes: row = 4*g + j
        int  oid[4];
        bool okw[4];
        #pragma unroll
        for (int j = 0; j < 4; ++j) {
            int r = rb + 4 * g + j;
            okw[j] = (r < U);
            oid[j] = ids[(r < U) ? r : (U - 1)];
        }
        // blend values (old h at this lane's output coords); L1-hot from the
        // hf gathers of sibling lanes/waves on this CU
        float hv[4];
        #pragma unroll
        for (int j = 0; j < 4; ++j)
            hv[j] = memory[(size_t)oid[j] * MEM_DIM + c];

        f32x4 acc[6];
        #pragma unroll
        for (int k = 0; k < 6; ++k) acc[k] = z4;

        #pragma unroll
        for (int s = 0; s < 8; ++s)
            #pragma unroll
            for (int gt = 0; gt < 3; ++gt)
                acc[gt] = __builtin_amdgcn_mfma_f32_16x16x32_bf16(xf[s], Bi[s][gt], acc[gt], 0, 0, 0);
        #pragma unroll
        for (int s = 0; s < 4; ++s)
            #pragma unroll
            for (int gt = 0; gt < 3; ++gt)
                acc[3 + gt] = __builtin_amdgcn_mfma_f32_16x16x32_bf16(hf[s], Bh[s][gt], acc[3 + gt], 0, 0, 0);

        // gate math + scatter store
        #pragma unroll
        for (int j = 0; j < 4; ++j) {
            if (okw[j]) {
                float gr = acc[0][j] + acc[3][j] + br;
                float gz = acc[1][j] + acc[4][j] + bz;
                float rg = sigm(gr);
                float zg = sigm(gz);
                float hn = acc[5][j] + bhn;
                float ng = tanh_fast(acc[2][j] + bin + rg * hn);
                out_mem[(size_t)oid[j] * MEM_DIM + c] = (1.0f - zg) * ng + zg * hv[j];
            }
        }
    }
}

// ------------------------------------------------------------------- launcher
extern "C" void kernel_launch(void* const* d_in, const int* in_sizes, int n_in,
                              void* d_out, int out_size, void* d_ws, size_t ws_size,
                              hipStream_t stream) {
    const float* memory      = (const float*)d_in[0];
    const float* last_update = (const float*)d_in[1];
    const int*   ids         = (const int*)  d_in[2];
    const float* msgs        = (const float*)d_in[3];
    const float* ts          = (const float*)d_in[4];
    const float* Wih         = (const float*)d_in[5];
    const float* Whh         = (const float*)d_in[6];
    const float* bih         = (const float*)d_in[7];
    const float* bhh         = (const float*)d_in[8];

    const int NN = in_sizes[1];          // 1,000,000 nodes
    const int U  = in_sizes[2];          // 200,000 updates

    float* out_mem = (float*)d_out;
    float* out_lu  = out_mem + (size_t)NN * MEM_DIM;

    const size_t WBYTES  = (size_t)(NGATE * MSG_DIM + NGATE * MEM_DIM) * sizeof(__hip_bfloat16);
    const size_t BM_OFF  = (WBYTES + 255) & ~(size_t)255;
    const int    BMWORDS = (NN + 31) / 32;
    const int    ntiles  = (U + 15) / 16;

    if (ws_size >= BM_OFF + (size_t)BMWORDS * 4) {
        __hip_bfloat16* wb = (__hip_bfloat16*)d_ws;
        uint32_t* bm = (uint32_t*)((char*)d_ws + BM_OFF);

        wconv_kernel<<<(NGATE * MSG_DIM + NGATE * MEM_DIM) / 256, 256, 0, stream>>>(Wih, Whh, wb);
        bm_zero_kernel<<<(BMWORDS + 255) / 256, 256, 0, stream>>>(bm, BMWORDS);
        bm_set_kernel<<<(U + 255) / 256, 256, 0, stream>>>(ids, bm, U);

        gru_ws_kernel<true><<<256, 512, 0, stream>>>(memory, ids, msgs, ts,
                                                     Wih, Whh, bih, bhh,
                                                     wb, wb + NGATE * MSG_DIM,
                                                     out_mem, out_lu, U, ntiles);

        copy_skip_kernel<<<8192, 256, 0, stream>>>((const f32x4*)memory, last_update,
                                                   (f32x4*)out_mem, out_lu, bm, NN);
    } else {
        // fallback: full copy first, GRU overwrites updated rows after
        int n_mem4 = NN * MEM_DIM / 4;
        int n_tot4 = n_mem4 + NN / 4;
        copy_all_kernel<<<8192, 256, 0, stream>>>((const f32x4*)memory,
                                                  (const f32x4*)last_update,
                                                  (f32x4*)d_out, n_mem4, n_tot4);
        gru_ws_kernel<false><<<256, 512, 0, stream>>>(memory, ids, msgs, ts,
                                                      Wih, Whh, bih, bhh,
                                                      nullptr, nullptr,
                                                      out_mem, out_lu, U, ntiles);
    }
}

// Round 6
// 412.593 us; speedup vs baseline: 1.7061x; 1.2084x over previous
//
#include <hip/hip_runtime.h>
#include <hip/hip_bf16.h>
#include <stdint.h>

#define MEM_DIM 128
#define MSG_DIM 256
#define NGATE   384          // 3 * MEM_DIM
#define NQ      512          // padded quantity rows: r | z | i_n | h_n
#define KTOT    384          // MSG_DIM + MEM_DIM
#define BM      64           // update rows per block
#define BK      32           // K elements per staged B slice
#define NKSTEP  (KTOT / BK)  // 12

typedef __attribute__((ext_vector_type(8))) __bf16 bf16x8;
typedef __attribute__((ext_vector_type(4))) float  f32x4;

union B8u { uint32_t u[4]; bf16x8 v; };

__device__ __forceinline__ uint32_t cvt_pk(float lo, float hi) {
    uint32_t r;
    asm("v_cvt_pk_bf16_f32 %0, %1, %2" : "=v"(r) : "v"(lo), "v"(hi));
    return r;
}

__device__ __forceinline__ bf16x8 load_cvt8(const float* __restrict__ p) {
    f32x4 a = *(const f32x4*)p;
    f32x4 b = *(const f32x4*)(p + 4);
    B8u r;
    r.u[0] = cvt_pk(a.x, a.y);
    r.u[1] = cvt_pk(a.z, a.w);
    r.u[2] = cvt_pk(b.x, b.y);
    r.u[3] = cvt_pk(b.z, b.w);
    return r.v;
}

__device__ __forceinline__ bf16x8 zero8() {
    B8u r; r.u[0] = r.u[1] = r.u[2] = r.u[3] = 0; return r.v;
}

__device__ __forceinline__ float sigm(float x) {
    return __builtin_amdgcn_rcpf(1.0f + __expf(-x));
}
__device__ __forceinline__ float tanh_fast(float x) {
    return 1.0f - 2.0f * __builtin_amdgcn_rcpf(1.0f + __expf(2.0f * x));
}

// ------------------------------------------------------------- bitmap kernels
__global__ void bm_zero_kernel(uint32_t* __restrict__ bm, int nwords) {
    int i = blockIdx.x * 256 + threadIdx.x;
    if (i < nwords) bm[i] = 0;
}
__global__ void bm_set_kernel(const int* __restrict__ ids, uint32_t* __restrict__ bm, int U) {
    int i = blockIdx.x * 256 + threadIdx.x;
    if (i < U) {
        int id = ids[i];
        atomicOr(&bm[id >> 5], 1u << (id & 31));
    }
}

// ----------------------------------------------- copy kernel (skips updated)
__global__ void copy_skip_kernel(const f32x4* __restrict__ mem,
                                 const float* __restrict__ lu,
                                 f32x4* __restrict__ outm,
                                 float* __restrict__ outlu,
                                 const uint32_t* __restrict__ bm,
                                 int NN) {
    const int64_t n_mem_chunks = (int64_t)NN * 32;   // 512 B rows / 16 B
    const int64_t total = n_mem_chunks + NN;
    const int64_t stride = (int64_t)gridDim.x * blockDim.x;
    for (int64_t i = (int64_t)blockIdx.x * blockDim.x + threadIdx.x; i < total; i += stride) {
        if (i < n_mem_chunks) {
            int row = (int)(i >> 5);
            if (!((bm[row >> 5] >> (row & 31)) & 1u)) {
                f32x4 v = __builtin_nontemporal_load(&mem[i]);
                __builtin_nontemporal_store(v, &outm[i]);
            }
        } else {
            int node = (int)(i - n_mem_chunks);
            if (!((bm[node >> 5] >> (node & 31)) & 1u))
                outlu[node] = lu[node];
        }
    }
}

// fallback full copy (no workspace for bitmap)
__global__ void copy_all_kernel(const f32x4* __restrict__ mem,
                                const f32x4* __restrict__ lu,
                                f32x4* __restrict__ out,
                                int n_mem4, int n_tot4) {
    int stride = gridDim.x * blockDim.x;
    for (int i = blockIdx.x * blockDim.x + threadIdx.x; i < n_tot4; i += stride) {
        f32x4 v = (i < n_mem4) ? mem[i]
                               : __builtin_nontemporal_load(&lu[i - n_mem4]);
        __builtin_nontemporal_store(v, &out[i]);
    }
}

// ------------------------------------------- Wcat bf16 build (padded layout)
// Wcat[512][384]: rows 0..127 = r (Wih_r | Whh_r), 128..255 = z,
// 256..383 = i_n (Wih_n | 0), 384..511 = h_n (0 | Whh_n)
__global__ void wcat_kernel(const float* __restrict__ wih,
                            const float* __restrict__ whh,
                            __hip_bfloat16* __restrict__ wcat) {
    int i = blockIdx.x * 256 + threadIdx.x;
    if (i >= NQ * KTOT) return;
    int lr = i / KTOT, k = i - lr * KTOT;
    int q = lr >> 7, c = lr & 127;
    float v;
    if (k < MSG_DIM) {
        int g = (q == 2) ? 2 : q;            // q3 -> zero
        v = (q == 3) ? 0.f : wih[(size_t)(g * MEM_DIM + c) * MSG_DIM + k];
    } else {
        int g = (q == 3) ? 2 : q;            // q2 -> zero
        v = (q == 2) ? 0.f : whh[(size_t)(g * MEM_DIM + c) * MEM_DIM + (k - MSG_DIM)];
    }
    wcat[i] = __float2bfloat16(v);
}

// -------------------------------------------------------------- GEMM-GRU
// Block: 512 threads = 8 waves, BM=64 rows, full 512 padded cols.
// At LDS: [64][384] bf16 (x||h), staged once. Bt LDS: [512][32] bf16 per step.
// Wave w owns mem-cols w*16..w*16+15 of all 4 quantities, all 64 rows:
// acc[4 Mtiles][4 q] = 64 VGPRs. Gate math wave-local.
__device__ __forceinline__ int at_addr(int row, int kbyte) {
    return (row * (KTOT * 2) + kbyte) ^ ((row & 7) << 4);
}
__device__ __forceinline__ int bt_addr(int lr, int kbyte) {
    return (lr * (BK * 2) + kbyte) ^ ((lr & 7) << 4);
}

template<bool PRE>
__global__ __launch_bounds__(512, 4)
void gru_gemm_kernel(const float* __restrict__ memory,
                     const int*   __restrict__ ids,
                     const float* __restrict__ msgs,
                     const float* __restrict__ ts,
                     const float* __restrict__ Wih,
                     const float* __restrict__ Whh,
                     const float* __restrict__ bih,
                     const float* __restrict__ bhh,
                     const __hip_bfloat16* __restrict__ Wcat,
                     float* __restrict__ out_mem,
                     float* __restrict__ out_lu,
                     int U) {
    __shared__ __align__(16) char At[BM * KTOT * 2];   // 49152 B
    __shared__ __align__(16) char Bt[NQ * BK * 2];     // 32768 B

    const int tid  = threadIdx.x;
    const int w    = tid >> 6;
    const int lane = tid & 63;
    const int lq   = lane & 15;
    const int lk   = lane >> 4;
    const int rb   = blockIdx.x * BM;

    // ---- timestamp scatter
    if (tid < BM) {
        int r = rb + tid;
        if (r < U) out_lu[ids[r]] = ts[r];
    }

    // ---- stage At: x part (all 512 threads: 8 per row)
    {
        int r = tid >> 3, seg = tid & 7;
        int rA = rb + r; if (rA >= U) rA = U - 1;
        const float* xp = msgs + (size_t)rA * MSG_DIM + seg * 32;
        #pragma unroll
        for (int i = 0; i < 4; ++i)
            *(bf16x8*)(At + at_addr(r, seg * 64 + i * 16)) = load_cvt8(xp + i * 8);
    }
    // ---- stage At: h part (256 threads: 4 per row)
    if (tid < 256) {
        int r = tid >> 2, seg = tid & 3;
        int rA = rb + r; if (rA >= U) rA = U - 1;
        const float* hp = memory + (size_t)ids[rA] * MEM_DIM + seg * 32;
        #pragma unroll
        for (int i = 0; i < 4; ++i)
            *(bf16x8*)(At + at_addr(r, 512 + seg * 64 + i * 16)) = load_cvt8(hp + i * 8);
    }

    // per-lane bias values (this wave's column), hoisted
    const int c = w * 16 + lq;
    const float br  = bih[c] + bhh[c];
    const float bz  = bih[MEM_DIM + c] + bhh[MEM_DIM + c];
    const float bin = bih[2 * MEM_DIM + c];
    const float bhn = bhh[2 * MEM_DIM + c];

    const f32x4 z4 = {0.f, 0.f, 0.f, 0.f};
    f32x4 acc[4][4];
    #pragma unroll
    for (int m = 0; m < 4; ++m)
        #pragma unroll
        for (int q = 0; q < 4; ++q) acc[m][q] = z4;

    // Bt staging config for this thread: permuted row (conflict-free writes)
    const int br_ = tid ^ ((tid & 1) << 2);
    const int bq  = br_ >> 7, bc = br_ & 127;

    // ---- K loop
    for (int ks = 0; ks < NKSTEP; ++ks) {
        __syncthreads();                 // previous compute done; Bt reusable
        // stage Bt[512][32] for this K slice
        if (PRE) {
            const __hip_bfloat16* wp = Wcat + (size_t)br_ * KTOT + ks * BK;
            #pragma unroll
            for (int i = 0; i < 4; ++i)
                *(bf16x8*)(Bt + bt_addr(br_, i * 16)) = *(const bf16x8*)(wp + i * 8);
        } else {
            bool isx = (ks < 8);
            bool zero = isx ? (bq == 3) : (bq == 2);
            const float* src;
            if (isx) {
                int g = (bq == 2) ? 2 : bq;
                src = Wih + (size_t)(g * MEM_DIM + bc) * MSG_DIM + ks * BK;
            } else {
                int g = (bq == 3) ? 2 : bq;
                src = Whh + (size_t)(g * MEM_DIM + bc) * MEM_DIM + (ks - 8) * BK;
            }
            #pragma unroll
            for (int i = 0; i < 4; ++i)
                *(bf16x8*)(Bt + bt_addr(br_, i * 16)) =
                    zero ? zero8() : load_cvt8(src + i * 8);
        }
        __syncthreads();                 // Bt ready

        // A fragments for the 4 M-tiles
        bf16x8 af[4];
        #pragma unroll
        for (int m = 0; m < 4; ++m)
            af[m] = *(const bf16x8*)(At + at_addr(m * 16 + lq, ks * 64 + lk * 16));

        #pragma unroll
        for (int q = 0; q < 4; ++q) {
            bf16x8 bf_ = *(const bf16x8*)(Bt + bt_addr(q * 128 + w * 16 + lq, lk * 16));
            #pragma unroll
            for (int m = 0; m < 4; ++m)
                acc[m][q] = __builtin_amdgcn_mfma_f32_16x16x32_bf16(af[m], bf_, acc[m][q], 0, 0, 0);
        }
    }

    // ---- epilogue: gate math + scatter (wave-local; h_old from At)
    #pragma unroll
    for (int m = 0; m < 4; ++m) {
        #pragma unroll
        for (int j = 0; j < 4; ++j) {
            int row = m * 16 + lk * 4 + j;
            int r = rb + row;
            if (r < U) {
                int id = ids[r];
                float hold = __bfloat162float(
                    *(const __hip_bfloat16*)(At + at_addr(row, 512 + c * 2)));
                float rg = sigm(acc[m][0][j] + br);
                float zg = sigm(acc[m][1][j] + bz);
                float ng = tanh_fast(acc[m][2][j] + bin + rg * (acc[m][3][j] + bhn));
                out_mem[(size_t)id * MEM_DIM + c] = (1.0f - zg) * ng + zg * hold;
            }
        }
    }
}

// ------------------------------------------------------------------- launcher
extern "C" void kernel_launch(void* const* d_in, const int* in_sizes, int n_in,
                              void* d_out, int out_size, void* d_ws, size_t ws_size,
                              hipStream_t stream) {
    const float* memory      = (const float*)d_in[0];
    const float* last_update = (const float*)d_in[1];
    const int*   ids         = (const int*)  d_in[2];
    const float* msgs        = (const float*)d_in[3];
    const float* ts          = (const float*)d_in[4];
    const float* Wih         = (const float*)d_in[5];
    const float* Whh         = (const float*)d_in[6];
    const float* bih         = (const float*)d_in[7];
    const float* bhh         = (const float*)d_in[8];

    const int NN = in_sizes[1];          // 1,000,000 nodes
    const int U  = in_sizes[2];          // 200,000 updates

    float* out_mem = (float*)d_out;
    float* out_lu  = out_mem + (size_t)NN * MEM_DIM;

    const size_t WCAT_BYTES = (size_t)NQ * KTOT * sizeof(__hip_bfloat16);  // 393216
    const size_t BM_OFF     = (WCAT_BYTES + 255) & ~(size_t)255;
    const int    BMWORDS    = (NN + 31) / 32;
    const int    nblocks    = (U + BM - 1) / BM;

    if (ws_size >= BM_OFF + (size_t)BMWORDS * 4) {
        __hip_bfloat16* wcat = (__hip_bfloat16*)d_ws;
        uint32_t* bm = (uint32_t*)((char*)d_ws + BM_OFF);

        wcat_kernel<<<(NQ * KTOT + 255) / 256, 256, 0, stream>>>(Wih, Whh, wcat);
        bm_zero_kernel<<<(BMWORDS + 255) / 256, 256, 0, stream>>>(bm, BMWORDS);
        bm_set_kernel<<<(U + 255) / 256, 256, 0, stream>>>(ids, bm, U);

        gru_gemm_kernel<true><<<nblocks, 512, 0, stream>>>(memory, ids, msgs, ts,
                                                           Wih, Whh, bih, bhh, wcat,
                                                           out_mem, out_lu, U);

        copy_skip_kernel<<<8192, 256, 0, stream>>>((const f32x4*)memory, last_update,
                                                   (f32x4*)out_mem, out_lu, bm, NN);
    } else {
        int n_mem4 = NN * MEM_DIM / 4;
        int n_tot4 = n_mem4 + NN / 4;
        copy_all_kernel<<<8192, 256, 0, stream>>>((const f32x4*)memory,
                                                  (const f32x4*)last_update,
                                                  (f32x4*)d_out, n_mem4, n_tot4);
        gru_gemm_kernel<false><<<nblocks, 512, 0, stream>>>(memory, ids, msgs, ts,
                                                            Wih, Whh, bih, bhh, nullptr,
                                                            out_mem, out_lu, U);
    }
}